// Round 3
// baseline (3098.997 us; speedup 1.0000x reference)
//
#include <hip/hip_runtime.h>
#include <cstddef>
#include <cstdint>

// Problem constants (from reference)
#define TOK    49      // N tokens (7x7)
#define KD     32      // key dim
#define NH     8       // heads
#define DHEAD  128     // v head dim (ATTN_RATIO*KEY_DIM)
#define HQKV   1536    // qkv output channels
#define DHTOT  1024    // NH*DHEAD
#define DIMM   384     // model dim

// ---------------------------------------------------------------------------
// SGEMM: C[M,N] = A[M,K] @ W[N,K]^T + bias[N]   (both operands K-contiguous)
// 256 threads, BM=BN=128, BK=16, 8x8 micro-tile per thread.
// M may be arbitrary (loads clamped, stores guarded). N, K multiples of tile.
// ---------------------------------------------------------------------------
template<int BM, int BN, int BK>
__global__ __launch_bounds__(256)
void sgemm_nt_bias(const float* __restrict__ A,
                   const float* __restrict__ W,
                   const float* __restrict__ bias,
                   float* __restrict__ C,
                   int M, int N, int K)
{
    __shared__ float As[BK][BM + 4];   // transposed: As[k][m]
    __shared__ float Ws[BK][BN + 4];   // transposed: Ws[k][n]

    const int t  = threadIdx.x;
    const int tn = t & 15;             // 16 col groups
    const int tm = t >> 4;             // 16 row groups
    const long bm = (long)blockIdx.x * BM;
    const long bn = (long)blockIdx.y * BN;

    float acc[8][8];
    #pragma unroll
    for (int i = 0; i < 8; ++i)
        #pragma unroll
        for (int j = 0; j < 8; ++j) acc[i][j] = 0.f;

    constexpr int KQ  = BK / 4;              // float4 chunks per row
    constexpr int LPT = (BM * KQ) / 256;     // float4 loads per thread

    for (int k0 = 0; k0 < K; k0 += BK) {
        #pragma unroll
        for (int l = 0; l < LPT; ++l) {
            int flat = t + l * 256;
            int row  = flat / KQ;
            int kq   = flat % KQ;
            long gr  = bm + row;
            if (gr >= M) gr = M - 1;          // clamped (safe) load
            float4 v = *reinterpret_cast<const float4*>(A + gr * (long)K + k0 + kq * 4);
            As[kq*4+0][row] = v.x;
            As[kq*4+1][row] = v.y;
            As[kq*4+2][row] = v.z;
            As[kq*4+3][row] = v.w;
        }
        #pragma unroll
        for (int l = 0; l < LPT; ++l) {
            int flat = t + l * 256;
            int row  = flat / KQ;
            int kq   = flat % KQ;
            float4 v = *reinterpret_cast<const float4*>(W + (bn + row) * (long)K + k0 + kq * 4);
            Ws[kq*4+0][row] = v.x;
            Ws[kq*4+1][row] = v.y;
            Ws[kq*4+2][row] = v.z;
            Ws[kq*4+3][row] = v.w;
        }
        __syncthreads();
        #pragma unroll
        for (int k = 0; k < BK; ++k) {
            float a[8], b[8];
            *reinterpret_cast<float4*>(&a[0]) = *reinterpret_cast<float4*>(&As[k][tm*8]);
            *reinterpret_cast<float4*>(&a[4]) = *reinterpret_cast<float4*>(&As[k][tm*8+4]);
            *reinterpret_cast<float4*>(&b[0]) = *reinterpret_cast<float4*>(&Ws[k][tn*8]);
            *reinterpret_cast<float4*>(&b[4]) = *reinterpret_cast<float4*>(&Ws[k][tn*8+4]);
            #pragma unroll
            for (int i = 0; i < 8; ++i)
                #pragma unroll
                for (int j = 0; j < 8; ++j)
                    acc[i][j] = fmaf(a[i], b[j], acc[i][j]);
        }
        __syncthreads();
    }

    float bv[8];
    *reinterpret_cast<float4*>(&bv[0]) = *reinterpret_cast<const float4*>(bias + bn + tn*8);
    *reinterpret_cast<float4*>(&bv[4]) = *reinterpret_cast<const float4*>(bias + bn + tn*8 + 4);

    #pragma unroll
    for (int i = 0; i < 8; ++i) {
        long row = bm + tm*8 + i;
        if (row < M) {
            float4 o0, o1;
            o0.x = acc[i][0] + bv[0]; o0.y = acc[i][1] + bv[1];
            o0.z = acc[i][2] + bv[2]; o0.w = acc[i][3] + bv[3];
            o1.x = acc[i][4] + bv[4]; o1.y = acc[i][5] + bv[5];
            o1.z = acc[i][6] + bv[6]; o1.w = acc[i][7] + bv[7];
            *reinterpret_cast<float4*>(C + row * (long)N + bn + tn*8)     = o0;
            *reinterpret_cast<float4*>(C + row * (long)N + bn + tn*8 + 4) = o1;
        }
    }
}

// ---------------------------------------------------------------------------
// Attention: one block per (batch, head). qkv row layout per token:
//   [h*192 + 0..31]=q, [h*192 + 32..63]=k, [h*192 + 64..191]=v
// Computes softmax(q k^T * scale + bias[h, idxs]) @ v -> attn_out[M, 1024]
// ---------------------------------------------------------------------------
__global__ __launch_bounds__(256)
void attn_kernel(const float* __restrict__ qkv,
                 const float* __restrict__ attn_bias,  // [NH, n_off]
                 const int*   __restrict__ bias_idxs,  // [49*49]
                 float* __restrict__ attn_out,         // [Mc, 1024]
                 int n_off)
{
    __shared__ float qs[TOK][KD];          // 49x32
    __shared__ float ks[TOK][KD];          // 49x32
    __shared__ float vs[TOK][DHEAD];       // 49x128
    __shared__ float S[TOK][TOK + 3];      // 49x52 (pad)

    const int t = threadIdx.x;
    const int b = blockIdx.x;
    const int h = blockIdx.y;

    const float* base = qkv + (size_t)b * TOK * HQKV + h * 192;

    // Load q,k,v for this (b,h): 49 rows x 192 floats (48 float4 per row)
    for (int flat = t; flat < TOK * 48; flat += 256) {
        int row = flat / 48;
        int c4  = flat % 48;
        float4 v = *reinterpret_cast<const float4*>(base + (size_t)row * HQKV + c4 * 4);
        int c = c4 * 4;
        if (c < KD) {
            *reinterpret_cast<float4*>(&qs[row][c]) = v;
        } else if (c < 2 * KD) {
            *reinterpret_cast<float4*>(&ks[row][c - KD]) = v;
        } else {
            *reinterpret_cast<float4*>(&vs[row][c - 2 * KD]) = v;
        }
    }
    __syncthreads();

    // Scores: S[n][m] = (q[n] . k[m]) * scale + bias
    const float scale = 0.17677669529663687f;  // 32^-0.5
    for (int s = t; s < TOK * TOK; s += 256) {
        int n = s / TOK, m = s % TOK;
        float acc = 0.f;
        #pragma unroll
        for (int kk = 0; kk < KD; kk += 4) {
            float4 qv = *reinterpret_cast<float4*>(&qs[n][kk]);
            float4 kv = *reinterpret_cast<float4*>(&ks[m][kk]);
            acc = fmaf(qv.x, kv.x, acc);
            acc = fmaf(qv.y, kv.y, acc);
            acc = fmaf(qv.z, kv.z, acc);
            acc = fmaf(qv.w, kv.w, acc);
        }
        float bia = attn_bias[h * n_off + bias_idxs[s]];
        S[n][m] = acc * scale + bia;
    }
    __syncthreads();

    // Softmax per row: 4 lanes per row (49*4 = 196 threads active)
    if (t < TOK * 4) {
        int n = t >> 2, j = t & 3;
        float mx = -1e30f;
        for (int m = j; m < TOK; m += 4) mx = fmaxf(mx, S[n][m]);
        mx = fmaxf(mx, __shfl_xor(mx, 1, 4));
        mx = fmaxf(mx, __shfl_xor(mx, 2, 4));
        float sum = 0.f;
        for (int m = j; m < TOK; m += 4) {
            float e = __expf(S[n][m] - mx);
            S[n][m] = e;
            sum += e;
        }
        sum += __shfl_xor(sum, 1, 4);
        sum += __shfl_xor(sum, 2, 4);
        float inv = 1.f / sum;
        for (int m = j; m < TOK; m += 4) S[n][m] *= inv;
    }
    __syncthreads();

    // PV: out[n][d] = sum_m S[n][m] * v[m][d]
    const int d4 = t & 31;
    const int nb = t >> 5;
    float4 acc[7];
    #pragma unroll
    for (int r = 0; r < 7; ++r) acc[r] = make_float4(0.f, 0.f, 0.f, 0.f);

    for (int m = 0; m < TOK; ++m) {
        float4 v = *reinterpret_cast<float4*>(&vs[m][d4 * 4]);
        #pragma unroll
        for (int r = 0; r < 7; ++r) {
            int n = nb + r * 8;
            if (n < TOK) {
                float p = S[n][m];
                acc[r].x = fmaf(p, v.x, acc[r].x);
                acc[r].y = fmaf(p, v.y, acc[r].y);
                acc[r].z = fmaf(p, v.z, acc[r].z);
                acc[r].w = fmaf(p, v.w, acc[r].w);
            }
        }
    }

    float* outb = attn_out + (size_t)b * TOK * DHTOT + h * DHEAD;
    #pragma unroll
    for (int r = 0; r < 7; ++r) {
        int n = nb + r * 8;
        if (n < TOK) {
            *reinterpret_cast<float4*>(outb + (size_t)n * DHTOT + d4 * 4) = acc[r];
        }
    }
}

// ---------------------------------------------------------------------------
extern "C" void kernel_launch(void* const* d_in, const int* in_sizes, int n_in,
                              void* d_out, int out_size, void* d_ws, size_t ws_size,
                              hipStream_t stream)
{
    const float* x         = (const float*)d_in[0];
    const float* qkv_w     = (const float*)d_in[1];  // [1536, 384]
    const float* qkv_b     = (const float*)d_in[2];  // [1536]
    const float* proj_w    = (const float*)d_in[3];  // [384, 1024]
    const float* proj_b    = (const float*)d_in[4];  // [384]
    const float* attn_bias = (const float*)d_in[5];  // [8, n_off]
    const int*   bias_idxs = (const int*)d_in[6];    // [49*49]

    const int Mtot  = in_sizes[0] / DIMM;            // B*N = 100352
    const int Btot  = Mtot / TOK;                    // 2048
    const int n_off = in_sizes[5] / NH;              // 49

    // Adaptive chunking: per-batch workspace = 49*(1536+1024)*4 bytes
    const size_t per_batch = (size_t)TOK * (HQKV + DHTOT) * sizeof(float);
    int Bc = (int)(ws_size / per_batch);
    if (Bc < 1) return;                              // cannot run at all
    if (Bc > Btot) Bc = Btot;

    for (int b0 = 0; b0 < Btot; b0 += Bc) {
        const int bc = (b0 + Bc <= Btot) ? Bc : (Btot - b0);
        const int Mc = bc * TOK;

        float* qkv_buf = (float*)d_ws;
        float* att_buf = qkv_buf + (size_t)Bc * TOK * HQKV;  // fixed offset (max chunk)

        const float* xc   = x + (size_t)b0 * TOK * DIMM;
        float*       outc = (float*)d_out + (size_t)b0 * TOK * DIMM;

        // 1) QKV projection: [Mc,384] @ [1536,384]^T + b -> [Mc,1536]
        sgemm_nt_bias<128, 128, 16>
            <<<dim3((Mc + 127) / 128, HQKV / 128), 256, 0, stream>>>(
                xc, qkv_w, qkv_b, qkv_buf, Mc, HQKV, DIMM);

        // 2) Attention per (batch, head) -> [Mc, 1024]
        attn_kernel<<<dim3(bc, NH), 256, 0, stream>>>(
            qkv_buf, attn_bias, bias_idxs, att_buf, n_off);

        // 3) Projection: [Mc,1024] @ [384,1024]^T + b -> [Mc,384]
        sgemm_nt_bias<128, 128, 16>
            <<<dim3((Mc + 127) / 128, DIMM / 128), 256, 0, stream>>>(
                att_buf, proj_w, proj_b, outc, Mc, DIMM, DHTOT);
    }
}

// Round 4
// 1137.571 us; speedup vs baseline: 2.7242x; 2.7242x over previous
//
#include <hip/hip_runtime.h>
#include <cstddef>
#include <cstdint>

#define TOK    49      // tokens (7x7)
#define KD     32      // key dim
#define NH     8       // heads
#define DHEAD  128     // v head dim
#define HQKV   1536    // qkv channels
#define DHTOT  1024    // NH*DHEAD
#define DIMM   384     // model dim

typedef float  f32x4  __attribute__((ext_vector_type(4)));
typedef __bf16 bf16x8 __attribute__((ext_vector_type(8)));

typedef const __attribute__((address_space(1))) void gas_void;
typedef __attribute__((address_space(3))) void las_void;

static __device__ __forceinline__ unsigned short f2bf(float f) {
    unsigned int u = __builtin_bit_cast(unsigned int, f);
    unsigned int r = (u + 0x7fffu + ((u >> 16) & 1u)) >> 16;   // RNE
    return (unsigned short)r;
}
static __device__ __forceinline__ float bflo(unsigned int u) {
    return __builtin_bit_cast(float, u << 16);
}
static __device__ __forceinline__ float bfhi(unsigned int u) {
    return __builtin_bit_cast(float, u & 0xffff0000u);
}

// ---------------------------------------------------------------------------
// fp32 -> bf16 cast, 8 elems/thread/iter, grid-stride. n8 = count/8.
// ---------------------------------------------------------------------------
__global__ __launch_bounds__(256)
void cast_f32_to_bf16(const float* __restrict__ in, unsigned short* __restrict__ out, long n8)
{
    long i = (long)blockIdx.x * 256 + threadIdx.x;
    const long stride = (long)gridDim.x * 256;
    for (; i < n8; i += stride) {
        float4 v0 = reinterpret_cast<const float4*>(in)[i * 2];
        float4 v1 = reinterpret_cast<const float4*>(in)[i * 2 + 1];
        uint4 o;
        o.x = f2bf(v0.x) | ((unsigned)f2bf(v0.y) << 16);
        o.y = f2bf(v0.z) | ((unsigned)f2bf(v0.w) << 16);
        o.z = f2bf(v1.x) | ((unsigned)f2bf(v1.y) << 16);
        o.w = f2bf(v1.z) | ((unsigned)f2bf(v1.w) << 16);
        reinterpret_cast<uint4*>(out)[i] = o;
    }
}

// ---------------------------------------------------------------------------
// bf16 MFMA GEMM: C[M,N] = A[M,K] @ W[N,K]^T + bias[N]
// m97 structure: 128x128 tile, BK=64, 4 waves x (4x4) 16x16x32 frags,
// global_load_lds width-16 staging, linear LDS [128][64] bf16.
// M, N multiples of 128; K multiple of 64.
// ---------------------------------------------------------------------------
template<bool BF16_OUT>
__global__ __launch_bounds__(256)
void gemm_bf16_nt(const unsigned short* __restrict__ A,   // [M][K] bf16
                  const unsigned short* __restrict__ W,   // [N][K] bf16
                  const float* __restrict__ bias,         // [N] fp32
                  void* __restrict__ Cv, int M, int N, int K)
{
    __shared__ unsigned short Alds[128 * 64];
    __shared__ unsigned short Blds[128 * 64];

    const int t    = threadIdx.x;
    const int lane = t & 63;
    const int wv   = t >> 6;           // wave 0..3
    const int wr   = wv >> 1;          // wave row quadrant
    const int wc   = wv & 1;           // wave col quadrant
    const long bm  = (long)blockIdx.x * 128;
    const long bn  = (long)blockIdx.y * 128;

    const int lrow = lane >> 3;        // 0..7 row within 8-row chunk
    const int lcol = (lane & 7) * 8;   // element col within 64

    const int frow = lane & 15;        // fragment row/col
    const int fk   = (lane >> 4) * 8;  // fragment k offset

    f32x4 acc[4][4];
    #pragma unroll
    for (int mi = 0; mi < 4; ++mi)
        #pragma unroll
        for (int ni = 0; ni < 4; ++ni)
            acc[mi][ni] = (f32x4)0.0f;

    for (int k0 = 0; k0 < K; k0 += 64) {
        // stage A,B tiles: 16 chunks of 8 rows each; wave handles 4 chunks per operand
        #pragma unroll
        for (int i = 0; i < 4; ++i) {
            const int c   = i * 4 + wv;
            const int row = c * 8 + lrow;
            const unsigned short* ga = A + (bm + row) * (size_t)K + k0 + lcol;
            __builtin_amdgcn_global_load_lds((gas_void*)ga, (las_void*)(Alds + c * 512), 16, 0, 0);
            const unsigned short* gb = W + (bn + row) * (size_t)K + k0 + lcol;
            __builtin_amdgcn_global_load_lds((gas_void*)gb, (las_void*)(Blds + c * 512), 16, 0, 0);
        }
        __syncthreads();   // compiler drains vmcnt before barrier

        #pragma unroll
        for (int ks = 0; ks < 64; ks += 32) {
            bf16x8 af[4], bfr[4];
            #pragma unroll
            for (int mi = 0; mi < 4; ++mi)
                af[mi] = *reinterpret_cast<const bf16x8*>(&Alds[(wr * 64 + mi * 16 + frow) * 64 + ks + fk]);
            #pragma unroll
            for (int ni = 0; ni < 4; ++ni)
                bfr[ni] = *reinterpret_cast<const bf16x8*>(&Blds[(wc * 64 + ni * 16 + frow) * 64 + ks + fk]);
            #pragma unroll
            for (int mi = 0; mi < 4; ++mi)
                #pragma unroll
                for (int ni = 0; ni < 4; ++ni)
                    acc[mi][ni] = __builtin_amdgcn_mfma_f32_16x16x32_bf16(af[mi], bfr[ni], acc[mi][ni], 0, 0, 0);
        }
        __syncthreads();
    }

    // Epilogue: C/D layout col=lane&15, row=(lane>>4)*4+j  [verified m89/m91]
    const int rbase = (lane >> 4) * 4;
    #pragma unroll
    for (int ni = 0; ni < 4; ++ni) {
        const long col = bn + wc * 64 + ni * 16 + frow;
        const float bv = bias[col];
        #pragma unroll
        for (int mi = 0; mi < 4; ++mi) {
            #pragma unroll
            for (int j = 0; j < 4; ++j) {
                const long row = bm + wr * 64 + mi * 16 + rbase + j;
                const float v = acc[mi][ni][j] + bv;
                if (BF16_OUT) ((unsigned short*)Cv)[row * (size_t)N + col] = f2bf(v);
                else          ((float*)Cv)[row * (size_t)N + col] = v;
            }
        }
    }
}

// ---------------------------------------------------------------------------
// Attention: one block per (batch, head). bf16 in (qkv [Mc][1536]), bf16 out.
// Internals fp32 in LDS (VALU). Row layout per token: h*192 + [q32|k32|v128].
// ---------------------------------------------------------------------------
__global__ __launch_bounds__(256)
void attn_kernel(const unsigned short* __restrict__ qkv,
                 const float* __restrict__ attn_bias,  // [NH, n_off]
                 const int*   __restrict__ bias_idxs,  // [49*49]
                 unsigned short* __restrict__ attn_out,// [Mc][1024] bf16
                 int n_off)
{
    __shared__ float qs[TOK][KD];
    __shared__ float ks[TOK][KD];
    __shared__ float vs[TOK][DHEAD];
    __shared__ float S[TOK][TOK + 3];

    const int t = threadIdx.x;
    const int b = blockIdx.x;
    const int h = blockIdx.y;

    const unsigned short* base = qkv + (size_t)b * TOK * HQKV + h * 192;

    // Load+convert q,k,v: 49 rows x 24 chunks of 8 bf16
    for (int flat = t; flat < TOK * 24; flat += 256) {
        int row = flat / 24, c8 = flat % 24;
        uint4 u = *reinterpret_cast<const uint4*>(base + (size_t)row * HQKV + c8 * 8);
        int c = c8 * 8;
        float4 lo = make_float4(bflo(u.x), bfhi(u.x), bflo(u.y), bfhi(u.y));
        float4 hi = make_float4(bflo(u.z), bfhi(u.z), bflo(u.w), bfhi(u.w));
        float* dst;
        if (c < KD)          dst = &qs[row][c];
        else if (c < 2 * KD) dst = &ks[row][c - KD];
        else                 dst = &vs[row][c - 2 * KD];
        *reinterpret_cast<float4*>(dst)     = lo;
        *reinterpret_cast<float4*>(dst + 4) = hi;
    }
    __syncthreads();

    // Scores
    const float scale = 0.17677669529663687f;  // 32^-0.5
    for (int s = t; s < TOK * TOK; s += 256) {
        int n = s / TOK, m = s % TOK;
        float acc = 0.f;
        #pragma unroll
        for (int kk = 0; kk < KD; kk += 4) {
            float4 qv = *reinterpret_cast<float4*>(&qs[n][kk]);
            float4 kv = *reinterpret_cast<float4*>(&ks[m][kk]);
            acc = fmaf(qv.x, kv.x, acc);
            acc = fmaf(qv.y, kv.y, acc);
            acc = fmaf(qv.z, kv.z, acc);
            acc = fmaf(qv.w, kv.w, acc);
        }
        S[n][m] = acc * scale + attn_bias[h * n_off + bias_idxs[s]];
    }
    __syncthreads();

    // Softmax: 4 lanes per row
    if (t < TOK * 4) {
        int n = t >> 2, j = t & 3;
        float mx = -1e30f;
        for (int m = j; m < TOK; m += 4) mx = fmaxf(mx, S[n][m]);
        mx = fmaxf(mx, __shfl_xor(mx, 1, 4));
        mx = fmaxf(mx, __shfl_xor(mx, 2, 4));
        float sum = 0.f;
        for (int m = j; m < TOK; m += 4) {
            float e = __expf(S[n][m] - mx);
            S[n][m] = e;
            sum += e;
        }
        sum += __shfl_xor(sum, 1, 4);
        sum += __shfl_xor(sum, 2, 4);
        float inv = 1.f / sum;
        for (int m = j; m < TOK; m += 4) S[n][m] *= inv;
    }
    __syncthreads();

    // PV
    const int d4 = t & 31;
    const int nb = t >> 5;
    float4 acc[7];
    #pragma unroll
    for (int r = 0; r < 7; ++r) acc[r] = make_float4(0.f, 0.f, 0.f, 0.f);

    for (int m = 0; m < TOK; ++m) {
        float4 v = *reinterpret_cast<float4*>(&vs[m][d4 * 4]);
        #pragma unroll
        for (int r = 0; r < 7; ++r) {
            int n = nb + r * 8;
            if (n < TOK) {
                float p = S[n][m];
                acc[r].x = fmaf(p, v.x, acc[r].x);
                acc[r].y = fmaf(p, v.y, acc[r].y);
                acc[r].z = fmaf(p, v.z, acc[r].z);
                acc[r].w = fmaf(p, v.w, acc[r].w);
            }
        }
    }

    unsigned short* outb = attn_out + (size_t)b * TOK * DHTOT + h * DHEAD;
    #pragma unroll
    for (int r = 0; r < 7; ++r) {
        int n = nb + r * 8;
        if (n < TOK) {
            uint2 o;
            o.x = f2bf(acc[r].x) | ((unsigned)f2bf(acc[r].y) << 16);
            o.y = f2bf(acc[r].z) | ((unsigned)f2bf(acc[r].w) << 16);
            *reinterpret_cast<uint2*>(outb + (size_t)n * DHTOT + d4 * 4) = o;
        }
    }
}

// ---------------------------------------------------------------------------
extern "C" void kernel_launch(void* const* d_in, const int* in_sizes, int n_in,
                              void* d_out, int out_size, void* d_ws, size_t ws_size,
                              hipStream_t stream)
{
    const float* x         = (const float*)d_in[0];
    const float* qkv_w     = (const float*)d_in[1];  // [1536, 384]
    const float* qkv_b     = (const float*)d_in[2];  // [1536]
    const float* proj_w    = (const float*)d_in[3];  // [384, 1024]
    const float* proj_b    = (const float*)d_in[4];  // [384]
    const float* attn_bias = (const float*)d_in[5];  // [8, n_off]
    const int*   bias_idxs = (const int*)d_in[6];    // [49*49]

    const int Mtot  = in_sizes[0] / DIMM;            // 100352
    const int Btot  = Mtot / TOK;                    // 2048
    const int n_off = in_sizes[5] / NH;              // 49

    unsigned short* ws = (unsigned short*)d_ws;
    const size_t nWq = (size_t)HQKV * DIMM;          // 589824
    const size_t nWp = (size_t)DIMM * DHTOT;         // 393216
    unsigned short* wq  = ws;
    unsigned short* wp  = wq + nWq;
    unsigned short* dyn = wp + nWp;
    const size_t fixed_bytes = (nWq + nWp) * sizeof(unsigned short);
    const size_t per_batch   = (size_t)TOK * (DIMM + HQKV + DHTOT) * sizeof(unsigned short);

    if (ws_size <= fixed_bytes) return;
    long BcL = (long)((ws_size - fixed_bytes) / per_batch);
    int Bc = (int)((BcL / 128) * 128);   // Mc = Bc*49 must be multiple of 128
    if (Bc <= 0) return;                 // (round-3 evidence: ws >= 1.03 GB, never hit)
    if (Bc > Btot) Bc = Btot;

    // Cast weights to bf16 once
    cast_f32_to_bf16<<<dim3(64), 256, 0, stream>>>(qkv_w, wq, (long)(nWq / 8));
    cast_f32_to_bf16<<<dim3(64), 256, 0, stream>>>(proj_w, wp, (long)(nWp / 8));

    for (int b0 = 0; b0 < Btot; b0 += Bc) {
        const int bc = (b0 + Bc <= Btot) ? Bc : (Btot - b0);  // multiple of 128
        const int Mc = bc * TOK;                              // multiple of 6272 (=49*128)

        unsigned short* xb = dyn;
        unsigned short* qb = xb + (size_t)Bc * TOK * DIMM;
        unsigned short* ab = qb + (size_t)Bc * TOK * HQKV;

        const float* xc   = x + (size_t)b0 * TOK * DIMM;
        float*       outc = (float*)d_out + (size_t)b0 * TOK * DIMM;

        // 0) cast x chunk to bf16
        cast_f32_to_bf16<<<dim3(2048), 256, 0, stream>>>(xc, xb, (long)Mc * DIMM / 8);

        // 1) QKV: [Mc,384]x[1536,384]^T + b -> bf16 [Mc,1536]
        gemm_bf16_nt<true><<<dim3(Mc / 128, HQKV / 128), 256, 0, stream>>>(
            xb, wq, qkv_b, qb, Mc, HQKV, DIMM);

        // 2) attention -> bf16 [Mc,1024]
        attn_kernel<<<dim3(bc, NH), 256, 0, stream>>>(
            qb, attn_bias, bias_idxs, ab, n_off);

        // 3) proj: [Mc,1024]x[384,1024]^T + b -> fp32 out
        gemm_bf16_nt<false><<<dim3(Mc / 128, DIMM / 128), 256, 0, stream>>>(
            ab, wp, proj_b, outc, Mc, DIMM, DHTOT);
    }
}

// Round 5
// 806.683 us; speedup vs baseline: 3.8417x; 1.4102x over previous
//
#include <hip/hip_runtime.h>
#include <cstddef>
#include <cstdint>

#define TOK    49      // tokens (7x7)
#define KD     32      // key dim
#define NH     8       // heads
#define DHEAD  128     // v head dim
#define HQKV   1536    // qkv channels
#define DHTOT  1024    // NH*DHEAD
#define DIMM   384     // model dim

typedef unsigned short u16;
typedef float  f32x4  __attribute__((ext_vector_type(4)));
typedef __bf16 bf16x8 __attribute__((ext_vector_type(8)));

typedef const __attribute__((address_space(1))) void gas_void;
typedef __attribute__((address_space(3))) void las_void;

static __device__ __forceinline__ u16 f2bf(float f) {
    unsigned int u = __builtin_bit_cast(unsigned int, f);
    unsigned int r = (u + 0x7fffu + ((u >> 16) & 1u)) >> 16;   // RNE
    return (u16)r;
}

// XOR-swizzled index into a row-major [*][64] bf16 image: 8-short (16B) slots,
// slot ^= (row&7). Same formula on write (GEMM epilogue, global) and read
// (attn LDS frags) — staging is a linear copy, so images coincide.
static __device__ __forceinline__ int swz(int row, int c) {
    return (row << 6) + ((((c >> 3) ^ (row & 7)) << 3) | (c & 7));
}

// ---------------------------------------------------------------------------
// fp32 -> bf16 cast, 8 elems/thread/iter, grid-stride. n8 = count/8.
// ---------------------------------------------------------------------------
__global__ __launch_bounds__(256)
void cast_f32_to_bf16(const float* __restrict__ in, u16* __restrict__ out, long n8)
{
    long i = (long)blockIdx.x * 256 + threadIdx.x;
    const long stride = (long)gridDim.x * 256;
    for (; i < n8; i += stride) {
        float4 v0 = reinterpret_cast<const float4*>(in)[i * 2];
        float4 v1 = reinterpret_cast<const float4*>(in)[i * 2 + 1];
        uint4 o;
        o.x = f2bf(v0.x) | ((unsigned)f2bf(v0.y) << 16);
        o.y = f2bf(v0.z) | ((unsigned)f2bf(v0.w) << 16);
        o.z = f2bf(v1.x) | ((unsigned)f2bf(v1.y) << 16);
        o.w = f2bf(v1.z) | ((unsigned)f2bf(v1.w) << 16);
        reinterpret_cast<uint4*>(out)[i] = o;
    }
}

// ---------------------------------------------------------------------------
// bias_full[h][n*49+m] = attn_bias[h][bias_idxs[n*49+m]]
// ---------------------------------------------------------------------------
__global__ __launch_bounds__(256)
void bias_expand(const float* __restrict__ attn_bias, const int* __restrict__ idxs,
                 float* __restrict__ bias_full, int n_off)
{
    int i = blockIdx.x * 256 + threadIdx.x;
    if (i < NH * TOK * TOK) {
        int h = i / (TOK * TOK), s = i - h * (TOK * TOK);
        bias_full[i] = attn_bias[h * n_off + idxs[s]];
    }
}

// ---------------------------------------------------------------------------
// QKV GEMM: [M,384] @ [1536,384]^T + bias, routing epilogue:
//   q,k -> qkb[(b*8+h)][64 rows x 64 cols bf16, swizzled]   (q c=0..31, k c=32..63)
//   v   -> vt [(b*8+h)][128 rows (d) x 64 cols (n), swizzled]  (transposed!)
// m97 structure: 128x128 tile, BK=64, 4 waves x 4x4 16x16x32 frags.
// ---------------------------------------------------------------------------
__global__ __launch_bounds__(256)
void gemm_qkv(const u16* __restrict__ A,      // [M][384] bf16
              const u16* __restrict__ W,      // [1536][384] bf16
              const float* __restrict__ bias, // [1536]
              u16* __restrict__ qkb, u16* __restrict__ vt, int M)
{
    const int K = DIMM, N = HQKV;
    __shared__ u16 Alds[128 * 64];
    __shared__ u16 Blds[128 * 64];

    const int t    = threadIdx.x;
    const int lane = t & 63;
    const int wv   = t >> 6;
    const int wr   = wv >> 1;
    const int wc   = wv & 1;
    const int bm   = blockIdx.x * 128;
    const int bn   = blockIdx.y * 128;

    const int lrow = lane >> 3;
    const int lcol = (lane & 7) * 8;
    const int frow = lane & 15;
    const int fk   = (lane >> 4) * 8;

    f32x4 acc[4][4];
    #pragma unroll
    for (int mi = 0; mi < 4; ++mi)
        #pragma unroll
        for (int ni = 0; ni < 4; ++ni) acc[mi][ni] = (f32x4)0.0f;

    for (int k0 = 0; k0 < K; k0 += 64) {
        #pragma unroll
        for (int i = 0; i < 4; ++i) {
            const int c   = i * 4 + wv;
            const int row = c * 8 + lrow;
            __builtin_amdgcn_global_load_lds((gas_void*)(A + (size_t)(bm + row) * K + k0 + lcol),
                                             (las_void*)(Alds + c * 512), 16, 0, 0);
            __builtin_amdgcn_global_load_lds((gas_void*)(W + (size_t)(bn + row) * K + k0 + lcol),
                                             (las_void*)(Blds + c * 512), 16, 0, 0);
        }
        __syncthreads();
        #pragma unroll
        for (int ks = 0; ks < 64; ks += 32) {
            bf16x8 af[4], bf[4];
            #pragma unroll
            for (int mi = 0; mi < 4; ++mi)
                af[mi] = *reinterpret_cast<const bf16x8*>(&Alds[(wr * 64 + mi * 16 + frow) * 64 + ks + fk]);
            #pragma unroll
            for (int ni = 0; ni < 4; ++ni)
                bf[ni] = *reinterpret_cast<const bf16x8*>(&Blds[(wc * 64 + ni * 16 + frow) * 64 + ks + fk]);
            #pragma unroll
            for (int mi = 0; mi < 4; ++mi)
                #pragma unroll
                for (int ni = 0; ni < 4; ++ni)
                    acc[mi][ni] = __builtin_amdgcn_mfma_f32_16x16x32_bf16(af[mi], bf[ni], acc[mi][ni], 0, 0, 0);
        }
        __syncthreads();
    }

    const int rbase = lane >> 4 ? (lane >> 4) * 4 : 0;  // (lane>>4)*4
    #pragma unroll
    for (int ni = 0; ni < 4; ++ni) {
        const int col = bn + wc * 64 + ni * 16 + frow;   // qkv channel
        const float bv = bias[col];
        const int h = col / 192;
        const int r = col - h * 192;
        #pragma unroll
        for (int mi = 0; mi < 4; ++mi) {
            #pragma unroll
            for (int j = 0; j < 4; ++j) {
                const int row = bm + wr * 64 + mi * 16 + rbase + j;   // token index
                const int bb = row / TOK;
                const int n  = row - bb * TOK;
                const u16 val = f2bf(acc[mi][ni][j] + bv);
                if (r < 64) {
                    qkb[(size_t)(bb * NH + h) * 4096 + swz(n, r)] = val;
                } else {
                    vt[(size_t)(bb * NH + h) * 8192 + swz(r - 64, n)] = val;
                }
            }
        }
    }
}

// ---------------------------------------------------------------------------
// Generic bf16 GEMM (proj): C[M,N] = A @ W^T + bias, fp32 out.
// ---------------------------------------------------------------------------
__global__ __launch_bounds__(256)
void gemm_bf16_nt(const u16* __restrict__ A, const u16* __restrict__ W,
                  const float* __restrict__ bias, float* __restrict__ C,
                  int M, int N, int K)
{
    __shared__ u16 Alds[128 * 64];
    __shared__ u16 Blds[128 * 64];

    const int t    = threadIdx.x;
    const int lane = t & 63;
    const int wv   = t >> 6;
    const int wr   = wv >> 1;
    const int wc   = wv & 1;
    const int bm   = blockIdx.x * 128;
    const int bn   = blockIdx.y * 128;

    const int lrow = lane >> 3;
    const int lcol = (lane & 7) * 8;
    const int frow = lane & 15;
    const int fk   = (lane >> 4) * 8;

    f32x4 acc[4][4];
    #pragma unroll
    for (int mi = 0; mi < 4; ++mi)
        #pragma unroll
        for (int ni = 0; ni < 4; ++ni) acc[mi][ni] = (f32x4)0.0f;

    for (int k0 = 0; k0 < K; k0 += 64) {
        #pragma unroll
        for (int i = 0; i < 4; ++i) {
            const int c   = i * 4 + wv;
            const int row = c * 8 + lrow;
            __builtin_amdgcn_global_load_lds((gas_void*)(A + (size_t)(bm + row) * K + k0 + lcol),
                                             (las_void*)(Alds + c * 512), 16, 0, 0);
            __builtin_amdgcn_global_load_lds((gas_void*)(W + (size_t)(bn + row) * K + k0 + lcol),
                                             (las_void*)(Blds + c * 512), 16, 0, 0);
        }
        __syncthreads();
        #pragma unroll
        for (int ks = 0; ks < 64; ks += 32) {
            bf16x8 af[4], bf[4];
            #pragma unroll
            for (int mi = 0; mi < 4; ++mi)
                af[mi] = *reinterpret_cast<const bf16x8*>(&Alds[(wr * 64 + mi * 16 + frow) * 64 + ks + fk]);
            #pragma unroll
            for (int ni = 0; ni < 4; ++ni)
                bf[ni] = *reinterpret_cast<const bf16x8*>(&Blds[(wc * 64 + ni * 16 + frow) * 64 + ks + fk]);
            #pragma unroll
            for (int mi = 0; mi < 4; ++mi)
                #pragma unroll
                for (int ni = 0; ni < 4; ++ni)
                    acc[mi][ni] = __builtin_amdgcn_mfma_f32_16x16x32_bf16(af[mi], bf[ni], acc[mi][ni], 0, 0, 0);
        }
        __syncthreads();
    }

    const int rbase = (lane >> 4) * 4;
    #pragma unroll
    for (int ni = 0; ni < 4; ++ni) {
        const int col = bn + wc * 64 + ni * 16 + frow;
        const float bv = bias[col];
        #pragma unroll
        for (int mi = 0; mi < 4; ++mi) {
            #pragma unroll
            for (int j = 0; j < 4; ++j) {
                const int row = bm + wr * 64 + mi * 16 + rbase + j;
                C[(size_t)row * N + col] = acc[mi][ni][j] + bv;
            }
        }
    }
}

// ---------------------------------------------------------------------------
// MFMA attention. One block per (b,h), 256 threads / 4 waves.
// QKs: 64x64 bf16 swizzled (q|k per token row). Vt: 128x64 bf16 swizzled
// (row=d, col=n). S: f32 [64][80]. Ps: 64x64 bf16 swizzled.
// Wave w owns output rows 16w..16w+15.
// ---------------------------------------------------------------------------
__global__ __launch_bounds__(256)
void attn_mfma(const u16* __restrict__ qkb, const u16* __restrict__ vt,
               const float* __restrict__ bias_full,   // [NH][49*49]
               u16* __restrict__ ab)                  // [Mc][1024]
{
    __shared__ __align__(16) u16  QKs[64 * 64];
    __shared__ __align__(16) u16  Vts[128 * 64];
    __shared__ __align__(16) float S[64 * 80];
    __shared__ __align__(16) u16  Ps[64 * 64];

    const int t    = threadIdx.x;
    const int lane = t & 63;
    const int w    = t >> 6;
    const int fr   = lane & 15;
    const int fg   = lane >> 4;
    const int b    = blockIdx.x;
    const int h    = blockIdx.y;
    const int bh   = b * NH + h;

    // ---- stage swizzled images linearly (16B per lane) ----
    const u16* gq = qkb + (size_t)bh * 4096;
    const u16* gv = vt  + (size_t)bh * 8192;
    #pragma unroll
    for (int i = 0; i < 2; ++i)
        __builtin_amdgcn_global_load_lds((gas_void*)(gq + (i * 256 + t) * 8),
                                         (las_void*)(QKs + (i * 256 + w * 64) * 8), 16, 0, 0);
    #pragma unroll
    for (int i = 0; i < 4; ++i)
        __builtin_amdgcn_global_load_lds((gas_void*)(gv + (i * 256 + t) * 8),
                                         (las_void*)(Vts + (i * 256 + w * 64) * 8), 16, 0, 0);
    __syncthreads();

    // ---- QK^T: rows 16w.., all 64 cols; K=32 in one MFMA ----
    bf16x8 qf = *reinterpret_cast<const bf16x8*>(&QKs[swz(16 * w + fr, fg * 8)]);
    f32x4 sacc[4];
    #pragma unroll
    for (int nj = 0; nj < 4; ++nj) {
        bf16x8 kf = *reinterpret_cast<const bf16x8*>(&QKs[swz(16 * nj + fr, 32 + fg * 8)]);
        sacc[nj] = __builtin_amdgcn_mfma_f32_16x16x32_bf16(qf, kf, (f32x4)0.0f, 0, 0, 0);
    }

    // ---- S = sacc*scale + bias (clamped gather; invalid rows/cols unread) ----
    const float scale = 0.17677669529663687f;  // 32^-0.5
    const float* bh_bias = bias_full + h * (TOK * TOK);
    #pragma unroll
    for (int nj = 0; nj < 4; ++nj) {
        #pragma unroll
        for (int j = 0; j < 4; ++j) {
            const int row = 16 * w + fg * 4 + j;
            const int col = 16 * nj + fr;
            const int rn = row < TOK ? row : TOK - 1;
            const int cm = col < TOK ? col : TOK - 1;
            S[row * 80 + col] = sacc[nj][j] * scale + bh_bias[rn * TOK + cm];
        }
    }
    __syncthreads();

    // ---- softmax: 4 threads per row; thread j owns slots {j, j+4} ----
    {
        const int n = t >> 2;
        const int j = t & 3;
        const float* Sr = &S[n * 80];
        float v[16];
        #pragma unroll
        for (int e = 0; e < 8; ++e) v[e]     = Sr[8 * j + e];
        #pragma unroll
        for (int e = 0; e < 8; ++e) v[8 + e] = Sr[32 + 8 * j + e];

        float mx = -1e30f;
        #pragma unroll
        for (int e = 0; e < 8; ++e) mx = fmaxf(mx, v[e]);          // m = 8j+e < 32, valid
        #pragma unroll
        for (int e = 0; e < 8; ++e)
            if (32 + 8 * j + e < TOK) mx = fmaxf(mx, v[8 + e]);
        mx = fmaxf(mx, __shfl_xor(mx, 1, 4));
        mx = fmaxf(mx, __shfl_xor(mx, 2, 4));

        float sum = 0.f;
        #pragma unroll
        for (int e = 0; e < 8; ++e) { v[e] = __expf(v[e] - mx); sum += v[e]; }
        #pragma unroll
        for (int e = 0; e < 8; ++e) {
            const float ev = (32 + 8 * j + e < TOK) ? __expf(v[8 + e] - mx) : 0.f;
            v[8 + e] = ev; sum += ev;
        }
        sum += __shfl_xor(sum, 1, 4);
        sum += __shfl_xor(sum, 2, 4);
        const float inv = 1.f / sum;

        uint4 o;
        o.x = f2bf(v[0] * inv)  | ((unsigned)f2bf(v[1] * inv)  << 16);
        o.y = f2bf(v[2] * inv)  | ((unsigned)f2bf(v[3] * inv)  << 16);
        o.z = f2bf(v[4] * inv)  | ((unsigned)f2bf(v[5] * inv)  << 16);
        o.w = f2bf(v[6] * inv)  | ((unsigned)f2bf(v[7] * inv)  << 16);
        *reinterpret_cast<uint4*>(&Ps[swz(n, 8 * j)]) = o;
        o.x = f2bf(v[8] * inv)  | ((unsigned)f2bf(v[9] * inv)  << 16);
        o.y = f2bf(v[10] * inv) | ((unsigned)f2bf(v[11] * inv) << 16);
        o.z = f2bf(v[12] * inv) | ((unsigned)f2bf(v[13] * inv) << 16);
        o.w = f2bf(v[14] * inv) | ((unsigned)f2bf(v[15] * inv) << 16);
        *reinterpret_cast<uint4*>(&Ps[swz(n, 32 + 8 * j)]) = o;
    }
    __syncthreads();

    // ---- PV: O rows 16w.. x d 0..127; K=64 in 2 MFMA steps ----
    f32x4 oacc[8];
    #pragma unroll
    for (int nj = 0; nj < 8; ++nj) oacc[nj] = (f32x4)0.0f;
    #pragma unroll
    for (int ks = 0; ks < 2; ++ks) {
        bf16x8 pf = *reinterpret_cast<const bf16x8*>(&Ps[swz(16 * w + fr, ks * 32 + fg * 8)]);
        #pragma unroll
        for (int nj = 0; nj < 8; ++nj) {
            bf16x8 vf = *reinterpret_cast<const bf16x8*>(&Vts[swz(16 * nj + fr, ks * 32 + fg * 8)]);
            oacc[nj] = __builtin_amdgcn_mfma_f32_16x16x32_bf16(pf, vf, oacc[nj], 0, 0, 0);
        }
    }

    // ---- store O rows n<49 ----
    #pragma unroll
    for (int nj = 0; nj < 8; ++nj) {
        const int d = 16 * nj + fr;
        #pragma unroll
        for (int j = 0; j < 4; ++j) {
            const int n = 16 * w + fg * 4 + j;
            if (n < TOK)
                ab[((size_t)b * TOK + n) * DHTOT + h * DHEAD + d] = f2bf(oacc[nj][j]);
        }
    }
}

// ---------------------------------------------------------------------------
extern "C" void kernel_launch(void* const* d_in, const int* in_sizes, int n_in,
                              void* d_out, int out_size, void* d_ws, size_t ws_size,
                              hipStream_t stream)
{
    const float* x         = (const float*)d_in[0];
    const float* qkv_w     = (const float*)d_in[1];
    const float* qkv_b     = (const float*)d_in[2];
    const float* proj_w    = (const float*)d_in[3];
    const float* proj_b    = (const float*)d_in[4];
    const float* attn_bias = (const float*)d_in[5];
    const int*   bias_idxs = (const int*)d_in[6];

    const int Mtot  = in_sizes[0] / DIMM;            // 100352
    const int Btot  = Mtot / TOK;                    // 2048
    const int n_off = in_sizes[5] / NH;              // 49

    const size_t nWq = (size_t)HQKV * DIMM;
    const size_t nWp = (size_t)DIMM * DHTOT;
    float* bias_full = (float*)d_ws;                           // 8*2401 f32 = 76832 B
    u16*   wq        = (u16*)((char*)d_ws + 76832);
    u16*   wp        = wq + nWq;
    u16*   dyn       = wp + nWp;
    const size_t fixed_bytes = 76832 + (nWq + nWp) * sizeof(u16);
    // per-batch: xb 49*384*2 + qkb 8*4096*2 + vt 8*8192*2 + ab 49*1024*2
    const size_t per_batch = (size_t)TOK * DIMM * 2 + NH * 4096 * 2 + NH * 8192 * 2 + (size_t)TOK * DHTOT * 2;

    if (ws_size <= fixed_bytes) return;
    long BcL = (long)((ws_size - fixed_bytes) / per_batch);
    int Bc = (int)((BcL / 128) * 128);       // keep Mc multiple of 128
    if (Bc <= 0) return;
    if (Bc > Btot) Bc = Btot;                // round-3 evidence: ws >= 1.027 GB -> single chunk

    cast_f32_to_bf16<<<dim3(64), 256, 0, stream>>>(qkv_w, wq, (long)(nWq / 8));
    cast_f32_to_bf16<<<dim3(64), 256, 0, stream>>>(proj_w, wp, (long)(nWp / 8));
    bias_expand<<<dim3((NH * TOK * TOK + 255) / 256), 256, 0, stream>>>(attn_bias, bias_idxs, bias_full, n_off);

    for (int b0 = 0; b0 < Btot; b0 += Bc) {
        const int bc = (b0 + Bc <= Btot) ? Bc : (Btot - b0);   // multiple of 128
        const int Mc = bc * TOK;

        u16* xb  = dyn;
        u16* qkb = xb  + (size_t)Bc * TOK * DIMM;
        u16* vtb = qkb + (size_t)Bc * NH * 4096;
        u16* abb = vtb + (size_t)Bc * NH * 8192;

        const float* xc   = x + (size_t)b0 * TOK * DIMM;
        float*       outc = (float*)d_out + (size_t)b0 * TOK * DIMM;

        cast_f32_to_bf16<<<dim3(2048), 256, 0, stream>>>(xc, xb, (long)Mc * DIMM / 8);

        gemm_qkv<<<dim3(Mc / 128, HQKV / 128), 256, 0, stream>>>(xb, wq, qkv_b, qkb, vtb, Mc);

        attn_mfma<<<dim3(bc, NH), 256, 0, stream>>>(qkb, vtb, bias_full, abb);

        gemm_bf16_nt<<<dim3(Mc / 128, DIMM / 128), 256, 0, stream>>>(abb, wp, proj_b, outc, Mc, DIMM, DHTOT);
    }
}